// Round 9
// baseline (107.453 us; speedup 1.0000x reference)
//
#include <hip/hip_runtime.h>

#define S 128
#define LOG2E 1.4426950408889634f
#define LN2F  0.6931471805599453f

typedef float f4 __attribute__((ext_vector_type(4)));

static __device__ __forceinline__ float fexp2(float x) {
#if __has_builtin(__builtin_amdgcn_exp2f)
    return __builtin_amdgcn_exp2f(x);
#else
    return exp2f(x);
#endif
}
static __device__ __forceinline__ float flog2(float x) {
#if __has_builtin(__builtin_amdgcn_logf)
    return __builtin_amdgcn_logf(x);
#else
    return log2f(x);
#endif
}
// base-2 softplus: log2(1 + 2^x) = max(x,0) + log2(1 + 2^(-|x|))
static __device__ __forceinline__ float sp2(float x) {
    float a = fminf(x, -x);                 // -|x|
    float l = flog2(1.0f + fexp2(a));
    return fmaxf(x, 0.0f) + l;
}

// One block per (batch, i-pair): columns i0, i0+1. Grid = B*64 = 512 blocks =
// 2 resident blocks x 256 CU.
//
// Mask-aware load elision: row j dead (both columns' mc[j]==0) -> skip the
// whole 1KB s_sib row read; k-group dead (mc0[k0]==mc1[k0]==0, k0>0; dead k
// is a contiguous tail) -> skip that float4 pair. Skipped lanes keep sv=0,
// and fma(mc=0, sp2(0), acc) == acc exactly, so results are bit-identical
// to the unpredicated version; only HBM bytes change (~67MB -> ~40MB).
//
// Hat domain per column c (scaled by log2e; output multiplies back by ln2):
//   db1[k] = mc[k]*(pe1[k]-pe0[k]);  Kd = sum db1;  N = sum mc
//   Crow[j] = sum_k mc[k]*sp2(sv[j,k])
//   db2[j] = mc[j]*(dpe[j] + Kd + Crow[j] - N)
//   d2[k]  = db2[k] - db1[k]                         (j-independent)
//   T0 = sum_k mc[k]*sp2(d2);  T1 = sum_k mc[k]*d2
//   out[j,0] = ln2*mc[j]*(pe0[j] - T0)
//   out[j,1] = ln2*mc[j]*(pe1[j] + T1 - T0)
__global__ __launch_bounds__(1024, 8) void lbp_kernel(
    const float* __restrict__ s_edge,
    const float* __restrict__ s_sib,
    const unsigned char* __restrict__ mask_raw,
    float* __restrict__ out)
{
    const int iPair = blockIdx.x & 63;
    const int bb    = blockIdx.x >> 6;
    const int i0    = iPair * 2;
    const int t     = threadIdx.x;
    const int j     = t >> 3;
    const int gg    = t & 7;
    const int wid   = t >> 6;
    const int lane  = t & 63;

    __shared__ __align__(16) float s_mc [2][S];
    __shared__ __align__(16) float s_pe0[2][S];
    __shared__ __align__(16) float s_pe1[2][S];
    __shared__ __align__(16) float s_db1[2][S];
    __shared__ __align__(16) float s_db2[2][S];
    __shared__ float s_Kd[2], s_N[2];
    __shared__ int s_wf[16];

    // ---- mask dtype detect over first 4KB: one ballot flag per wave ----
    // bool8: nonzero bytes at %4!=0; int32(0/1): only %4==0 nonzero; f32: %4==3 byte 0x3F.
    {
        uchar4 v = ((const uchar4*)mask_raw)[t];
        int a1 = __any((v.y | v.z | v.w) != 0) ? 1 : 0;
        int a2 = __any(v.w == 0x3F) ? 2 : 0;
        if (lane == 0) s_wf[wid] = a1 | a2;
    }
    __syncthreads();                                           // (1)

    // ---- phase 0: both mask columns, scaled p_edge columns, db1 ----
    if (t < 2 * S) {
        const int c  = t >> 7;          // column 0/1
        const int jj = t & (S - 1);
        int flag = 0;
        #pragma unroll
        for (int w = 0; w < 16; ++w) flag |= s_wf[w];
        const int mode = (flag & 2) ? 2 : ((flag & 1) ? 0 : 1); // 2=f32,0=bool8,1=int32
        const int midx = (bb * S + jj) * S + i0 + c;
        int mval;
        if (mode == 0)      mval = mask_raw[midx];
        else if (mode == 1) mval = ((const int*)mask_raw)[midx];
        else                mval = (((const float*)mask_raw)[midx] != 0.0f);
        const float mc  = mval ? 1.0f : 0.0f;
        const float pe0 = s_edge[midx * 2]     * LOG2E;
        const float pe1 = s_edge[midx * 2 + 1] * LOG2E;
        s_mc [c][jj] = mc;
        s_pe0[c][jj] = pe0;
        s_pe1[c][jj] = pe1;
        s_db1[c][jj] = mc * (pe1 - pe0);
    }
    __syncthreads();                                           // (2)

    // waves 0,1: Kd/N for their column (overlaps other waves' Crow start)
    if (wid < 2) {
        float kd = s_db1[wid][lane] + s_db1[wid][lane + 64];
        float nn = s_mc [wid][lane] + s_mc [wid][lane + 64];
        #pragma unroll
        for (int o = 1; o < 64; o <<= 1) {
            kd += __shfl_xor(kd, o);
            nn += __shfl_xor(nn, o);
        }
        if (lane == 0) { s_Kd[wid] = kd; s_N[wid] = nn; }
    }

    // ---- Crow[j] both columns, with dead-row / dead-k load elision ----
    float acc0 = 0.0f, acc1 = 0.0f;
    const bool rowLive = (s_mc[0][j] != 0.0f) || (s_mc[1][j] != 0.0f);
    if (rowLive) {
        const f4* __restrict__ srow = (const f4*)(s_sib + ((bb * S + j) * S + i0) * S);
        #pragma unroll
        for (int r = 0; r < 4; ++r) {
            const int k0 = r * 32 + 4 * gg;
            const f4 m0 = *(const f4*)(&s_mc[0][k0]);
            const f4 m1 = *(const f4*)(&s_mc[1][k0]);
            f4 sv0 = {0.0f, 0.0f, 0.0f, 0.0f};
            f4 sv1 = {0.0f, 0.0f, 0.0f, 0.0f};
            if ((k0 == 0) || (m0.x != 0.0f) || (m1.x != 0.0f)) {
                sv0 = srow[r * 8 + gg];            // column i0
                sv1 = srow[32 + r * 8 + gg];       // column i0+1
            }
            acc0 = fmaf(m0.x, sp2(LOG2E * sv0.x), acc0);
            acc0 = fmaf(m0.y, sp2(LOG2E * sv0.y), acc0);
            acc0 = fmaf(m0.z, sp2(LOG2E * sv0.z), acc0);
            acc0 = fmaf(m0.w, sp2(LOG2E * sv0.w), acc0);
            acc1 = fmaf(m1.x, sp2(LOG2E * sv1.x), acc1);
            acc1 = fmaf(m1.y, sp2(LOG2E * sv1.y), acc1);
            acc1 = fmaf(m1.z, sp2(LOG2E * sv1.z), acc1);
            acc1 = fmaf(m1.w, sp2(LOG2E * sv1.w), acc1);
        }
    }
    acc0 += __shfl_xor(acc0, 1); acc1 += __shfl_xor(acc1, 1);
    acc0 += __shfl_xor(acc0, 2); acc1 += __shfl_xor(acc1, 2);
    acc0 += __shfl_xor(acc0, 4); acc1 += __shfl_xor(acc1, 4);
    __syncthreads();                                           // (3) Kd/N ready

    if (gg == 0) {
        const float mcj = s_mc[0][j];
        s_db2[0][j] = mcj * ((s_pe1[0][j] - s_pe0[0][j]) + s_Kd[0] + acc0 - s_N[0]);
    }
    if (gg == 1) {
        const float mcj = s_mc[1][j];
        s_db2[1][j] = mcj * ((s_pe1[1][j] - s_pe0[1][j]) + s_Kd[1] + acc1 - s_N[1]);
    }
    __syncthreads();                                           // (4)

    // ---- waves 0,1 tail: T0/T1 then both output rows per lane, per column ----
    if (wid < 2) {
        const int c = wid;
        const float mcA = s_mc[c][lane], mcB = s_mc[c][lane + 64];
        const float dA  = s_db2[c][lane]      - s_db1[c][lane];
        const float dB  = s_db2[c][lane + 64] - s_db1[c][lane + 64];
        float a0 = fmaf(mcA, sp2(dA), mcB * sp2(dB));
        float a1 = fmaf(mcA, dA, mcB * dB);
        #pragma unroll
        for (int o = 1; o < 64; o <<= 1) {
            a0 += __shfl_xor(a0, o);
            a1 += __shfl_xor(a1, o);
        }
        const int base = (bb * S) * S + i0 + c;
        {
            const float o0 = LN2F * mcA * (s_pe0[c][lane] - a0);
            const float o1 = LN2F * mcA * (s_pe1[c][lane] + a1 - a0);
            *(float2*)(out + (base + lane * S) * 2) = make_float2(o0, o1);
        }
        {
            const float o0 = LN2F * mcB * (s_pe0[c][lane + 64] - a0);
            const float o1 = LN2F * mcB * (s_pe1[c][lane + 64] + a1 - a0);
            *(float2*)(out + (base + (lane + 64) * S) * 2) = make_float2(o0, o1);
        }
    }
}

extern "C" void kernel_launch(void* const* d_in, const int* in_sizes, int n_in,
                              void* d_out, int out_size, void* d_ws, size_t ws_size,
                              hipStream_t stream) {
    const float* s_edge = (const float*)d_in[0];
    const float* s_sib  = (const float*)d_in[1];
    const unsigned char* mask = (const unsigned char*)d_in[2];
    float* out = (float*)d_out;

    const int B = in_sizes[0] / (S * S * 2);   // 8
    lbp_kernel<<<dim3(B * 64), dim3(1024), 0, stream>>>(s_edge, s_sib, mask, out);
}